// Round 6
// baseline (516.401 us; speedup 1.0000x reference)
//
#include <hip/hip_runtime.h>
#include <cstddef>
#include <cstdint>

#define TIME_N 262144
#define BATCH  32
#define KW     1024
#define ST     256
#define CUTN   513
#define TCN    1026
#define FN     1029   // frames
#define FPAD   1152
#define CPAD   1152
#define XLEN   (FPAD * ST + KW)   // 295936 bf16 per batch row
#define XBLK   (XLEN / 256)       // 1156

// mask GEMM dims
#define MROWS  (BATCH * FN)   // 32928
#define MP     33024          // 258*128
#define KPH    544            // 513 -> 17*32
#define NPH    640            // 513 -> 5*128
// convT GEMM dims / flat bf16 t layout (re/im PAIR-INTERLEAVED: col 2y=re_y, 2y+1=im_y)
#define TBP    1040           // flat bf16 t row stride (16B-aligned, 65*16)
#define FLATB  (FN * TBP)     // per-batch flat size
#define KPC    4160           // 4*1040 = 130*32

// k_prep block ranges
#define PB_XPAD  (XBLK * BATCH)            // 36992
#define PB_WBF   (PB_XPAD + CPAD)          // +1152
#define PB_WLIN  (PB_WBF + NPH)            // +640
#define PB_TOTAL (PB_WLIN + KPC)           // +4160

typedef __bf16 bf16x8 __attribute__((ext_vector_type(8)));
typedef float floatx4 __attribute__((ext_vector_type(4)));

__device__ __forceinline__ unsigned short f2bf(float f) {
    union { float f; unsigned u; } v; v.f = f;
    unsigned r = (v.u + 0x7fffu + ((v.u >> 16) & 1u)) >> 16;
    return (unsigned short)r;
}
__device__ __forceinline__ float bf2f(unsigned short s) {
    union { unsigned u; float f; } v; v.u = ((unsigned)s) << 16;
    return v.f;
}
// interleaved column n -> original channel index
__device__ __forceinline__ int permch(int n) {
    return (n & 1) ? (CUTN + (n >> 1)) : (n >> 1);
}

__device__ __forceinline__ void load_lds16(const void* g, void* l) {
    __builtin_amdgcn_global_load_lds(
        (const __attribute__((address_space(1))) void*)g,
        (__attribute__((address_space(3))) void*)l, 16, 0, 0);
}

// ---------------------------------------------------------------------------
// k_prep: all input-conversion work in ONE launch, split by blockIdx range.
// ---------------------------------------------------------------------------
__global__ __launch_bounds__(256) void k_prep(
    const float* __restrict__ x, const float* __restrict__ c1w,
    const float* __restrict__ lw, const float* __restrict__ wct,
    unsigned short* __restrict__ xb, unsigned short* __restrict__ wbf,
    unsigned short* __restrict__ wlb, unsigned short* __restrict__ wdb)
{
    const int bid = blockIdx.x;
    if (bid < PB_XPAD) {
        const int b = bid / XBLK;
        const int p = (bid - b * XBLK) * 256 + threadIdx.x;
        const int g = p - KW;
        float v = (g >= 0 && g < TIME_N) ? x[(size_t)b * TIME_N + g] : 0.0f;
        xb[(size_t)b * XLEN + p] = f2bf(v);
    } else if (bid < PB_WBF) {
        const int n = bid - PB_XPAD;              // 0..1151 interleaved row
        const int ch = (n < TCN) ? permch(n) : 0;
        for (int k = threadIdx.x; k < KW; k += 256) {
            float v = (n < TCN) ? c1w[(size_t)ch * KW + k] : 0.0f;
            wbf[(size_t)n * KW + k] = f2bf(v);
        }
    } else if (bid < PB_WLIN) {
        const int n = bid - PB_WBF;               // 0..639
        for (int k = threadIdx.x; k < KPH; k += 256) {
            float v = (n < CUTN && k < CUTN) ? lw[(size_t)n * CUTN + k] : 0.0f;
            wlb[(size_t)n * KPH + k] = f2bf(v);
        }
    } else {
        const int k = bid - PB_WLIN;              // 0..4159
        const int r = threadIdx.x;                // 0..255
        const int j = k / TBP;
        const int n = k - j * TBP;
        float v = 0.0f;
        if (n < TCN) {
            const int ch = permch(n);
            const int widx = (3 - j) * 256 + r;
            v = wct[(size_t)(2 * ch) * KW + widx] -
                wct[(size_t)(2 * ch + 1) * KW + widx];
        }
        wdb[(size_t)r * KPC + k] = f2bf(v);
    }
}

// ---------------------------------------------------------------------------
// k_conv1m (MFMA): conv1 bf16 GEMM, 128x128 tile, BK=32, double-buffered
// (2 x 16KB = 32KB LDS -> 5 blocks/CU: TLP restored; r5's 64KB capped at 2)
// with counted-vmcnt pipeline: issue tile t+1's 4 loads, s_waitcnt vmcnt(4)
// waits only tile t's, raw s_barrier (no drain). 64B-row LDS swizzle:
// byte ^= (((row>>1)&3)<<4)  (8 distinct bank-half x slot combos per 16
// lanes -> 2-way = free), via pre-swizzled global source + swizzled ds_read.
// XCD-chunked grid order (cb fastest within an XCD) kept from r5.
// ---------------------------------------------------------------------------
__global__ __launch_bounds__(256) void k_conv1m(
    const unsigned short* __restrict__ xb, const unsigned short* __restrict__ wb,
    const float* __restrict__ gamma,
    const float* __restrict__ c1w, const float* __restrict__ c1b,
    const float* __restrict__ c2w, const float* __restrict__ c2b,
    unsigned short* __restrict__ tb2, unsigned short* __restrict__ h)
{
    extern __shared__ __align__(16) char lds[];   // 2 x (A 8KB + B 8KB) = 32KB

    const int flat = blockIdx.x;
    const int xcd = flat & 7;
    const int idx = flat >> 3;              // 0..323
    const int cb  = idx % 9;
    const int pr  = xcd * 36 + idx / 9;     // 0..287 (b,fb) pair
    const int b   = pr / 9;
    const int fb  = pr % 9;
    const int f0 = fb * 128, c0 = cb * 128;
    const int tid = threadIdx.x;

    // staging: 512 chunks of 16B per operand; 2 chunks/thread/operand
    const unsigned short* xrow = xb + (size_t)b * XLEN;
    const unsigned short* ga[2];
    const unsigned short* gb[2];
    int qa[2];
#pragma unroll
    for (int i = 0; i < 2; ++i) {
        const int c = i * 256 + tid;             // chunk 0..511
        const int row = c >> 2;                  // 0..127
        const int colb = (c & 3) * 16;           // byte col in 64B row
        const int es = (colb ^ (((row >> 1) & 3) << 4)) >> 1;  // inv-swz elem
        qa[i] = c * 16;                          // linear LDS byte offset
        ga[i] = xrow + (size_t)(f0 + row) * ST + es;
        gb[i] = wb + (size_t)(c0 + row) * KW + es;
    }

    const int wave = tid >> 6, lane = tid & 63;
    const int lm = lane & 15, lq = lane >> 4;
    const int mw = (wave & 1) * 64, nw = (wave >> 1) * 64;
    const int swz = ((lm >> 1) & 3) << 4;
    const int abo = (mw + lm) * 64 + ((lq * 16) ^ swz);
    const int bbo = 8192 + (nw + lm) * 64 + ((lq * 16) ^ swz);

    floatx4 acc[4][4];
#pragma unroll
    for (int i = 0; i < 4; ++i)
#pragma unroll
        for (int j = 0; j < 4; ++j) acc[i][j] = (floatx4)0.0f;

    // prologue: issue K-tile 0 into buf 0 (4 loads in flight)
#pragma unroll
    for (int i = 0; i < 2; ++i) {
        load_lds16(ga[i], lds + qa[i]);
        load_lds16(gb[i], lds + 8192 + qa[i]);
        ga[i] += 32; gb[i] += 32;
    }

    for (int t = 0; t < KW / 32 - 1; ++t) {
        char* cur = lds + (t & 1) * 16384;
        char* nxt = lds + ((t + 1) & 1) * 16384;

        // issue tile t+1 (buffer freed by last iter's read-done barrier)
#pragma unroll
        for (int i = 0; i < 2; ++i) {
            load_lds16(ga[i], nxt + qa[i]);
            load_lds16(gb[i], nxt + 8192 + qa[i]);
            ga[i] += 32; gb[i] += 32;
        }
        // wait ONLY the oldest 4 (tile t); tile t+1's 4 stay in flight
        asm volatile("s_waitcnt vmcnt(4)" ::: "memory");
        __builtin_amdgcn_sched_barrier(0);
        __builtin_amdgcn_s_barrier();          // data-ready (no vmcnt drain)

        bf16x8 afr[4], bfr[4];
#pragma unroll
        for (int mt = 0; mt < 4; ++mt)
            afr[mt] = *(const bf16x8*)(cur + abo + mt * 1024);
#pragma unroll
        for (int nt = 0; nt < 4; ++nt)
            bfr[nt] = *(const bf16x8*)(cur + bbo + nt * 1024);
        asm volatile("s_waitcnt lgkmcnt(0)" ::: "memory");
        __builtin_amdgcn_sched_barrier(0);
        __builtin_amdgcn_s_barrier();          // reads done -> buffer reusable

        __builtin_amdgcn_s_setprio(1);
#pragma unroll
        for (int mt = 0; mt < 4; ++mt)
#pragma unroll
            for (int nt = 0; nt < 4; ++nt)
                acc[mt][nt] = __builtin_amdgcn_mfma_f32_16x16x32_bf16(
                    afr[mt], bfr[nt], acc[mt][nt], 0, 0, 0);
        __builtin_amdgcn_s_setprio(0);
    }
    // peeled final K-tile
    {
        char* cur = lds + ((KW / 32 - 1) & 1) * 16384;
        asm volatile("s_waitcnt vmcnt(0)" ::: "memory");
        __builtin_amdgcn_sched_barrier(0);
        __builtin_amdgcn_s_barrier();

        bf16x8 afr[4], bfr[4];
#pragma unroll
        for (int mt = 0; mt < 4; ++mt)
            afr[mt] = *(const bf16x8*)(cur + abo + mt * 1024);
#pragma unroll
        for (int nt = 0; nt < 4; ++nt)
            bfr[nt] = *(const bf16x8*)(cur + bbo + nt * 1024);
#pragma unroll
        for (int mt = 0; mt < 4; ++mt)
#pragma unroll
            for (int nt = 0; nt < 4; ++nt)
                acc[mt][nt] = __builtin_amdgcn_mfma_f32_16x16x32_bf16(
                    afr[mt], bfr[nt], acc[mt][nt], 0, 0, 0);
    }

    // epilogue
    float w1[16], b1[8], w2[8];
#pragma unroll
    for (int o = 0; o < 8; ++o) {
        w1[2 * o]     = c1w[2 * o];
        w1[2 * o + 1] = c1w[2 * o + 1];
        b1[o] = c1b[o];
        w2[o] = c2w[o];
    }
    const float b2v = c2b[0];

    unsigned short* tbb = tb2 + (size_t)b * FLATB;
    const bool evenlane = ((lane & 1) == 0);
#pragma unroll
    for (int nt = 0; nt < 4; ++nt) {
        const int n = c0 + nw + nt * 16 + lm;
        const bool valid_c = (n < TCN);
        const float gv = valid_c ? gamma[permch(n)] : 0.0f;
        const int nbase = n & ~1;
        const int ybase = n >> 1;
        const bool store_c = (nbase < TBP);
#pragma unroll
        for (int mt = 0; mt < 4; ++mt) {
#pragma unroll
            for (int rp = 0; rp < 2; ++rp) {
                const int ra = rp * 2;
                const int fa = f0 + mw + mt * 16 + lq * 4 + ra;
                const float ua = acc[mt][nt][ra] * gv;
                const float ub = acc[mt][nt][ra + 1] * gv;
                const float ta  = 2.0f / (1.0f + __expf(-2.0f * ua)) - 1.0f;
                const float tbv = 2.0f / (1.0f + __expf(-2.0f * ub)) - 1.0f;
                const float sa = __shfl_xor(ta, 1);
                const float sb = __shfl_xor(tbv, 1);
                // even lane owns frame fa with (re=ta, im=sa);
                // odd lane owns frame fa+1 with (re=sb, im=tbv)
                const int  fme = evenlane ? fa : (fa + 1);
                const float re = evenlane ? ta : sb;
                const float im = evenlane ? sa : tbv;
                if (fme < FN) {
                    if (store_c) {
                        const unsigned pr2 = (unsigned)f2bf(re) |
                                             ((unsigned)f2bf(im) << 16);
                        *(unsigned*)&tbb[(size_t)fme * TBP + nbase] = pr2;
                    }
                    if (valid_c) {
                        float a2 = b2v;
#pragma unroll
                        for (int o = 0; o < 8; ++o) {
                            const float a1 = fmaxf(
                                re * w1[2 * o] + im * w1[2 * o + 1] + b1[o], 0.0f);
                            a2 += a1 * w2[o];
                        }
                        h[((size_t)b * FN + fme) * KPH + ybase] =
                            f2bf(fmaxf(a2, 0.0f));
                    }
                }
            }
        }
    }
}

// ---------------------------------------------------------------------------
// k_maskm (MFMA): hh = H * Wlin^T; mask = sigmoid(2*(hh+b)*g);
// RMW: one aligned uint per (m,y) scales the (re,im) pair in tb2.
// (unchanged; KPH=544 is not divisible by 64)
// ---------------------------------------------------------------------------
__global__ __launch_bounds__(256) void k_maskm(
    const unsigned short* __restrict__ h, const unsigned short* __restrict__ wlb,
    const float* __restrict__ linb, const float* __restrict__ fcg,
    unsigned* __restrict__ tbu)
{
    __shared__ __align__(16) unsigned short As[128 * 32];
    __shared__ __align__(16) unsigned short Bs[128 * 32];

    const int m0 = blockIdx.x * 128, n0 = blockIdx.y * 128;
    const int tid = threadIdx.x;

    const int s0 = tid, s1 = tid + 256;
    const int ar0 = s0 >> 2, aq0 = s0 & 3;
    const int ar1 = s1 >> 2, aq1 = s1 & 3;
    const unsigned short* ga0 = h + (size_t)(m0 + ar0) * KPH + aq0 * 8;
    const unsigned short* ga1 = h + (size_t)(m0 + ar1) * KPH + aq1 * 8;
    const unsigned short* gb0 = wlb + (size_t)(n0 + ar0) * KPH + aq0 * 8;
    const unsigned short* gb1 = wlb + (size_t)(n0 + ar1) * KPH + aq1 * 8;
    unsigned short* la0 = &As[s0 * 8];
    unsigned short* la1 = &As[s1 * 8];
    unsigned short* lb0 = &Bs[s0 * 8];
    unsigned short* lb1 = &Bs[s1 * 8];

    const int wave = tid >> 6, lane = tid & 63;
    const int lm = lane & 15, lq = lane >> 4;
    const int mw = (wave & 1) * 64, nw = (wave >> 1) * 64;
    const unsigned short* Ap = &As[(mw + lm) * 32 + lq * 8];
    const unsigned short* Bp = &Bs[(nw + lm) * 32 + lq * 8];

    floatx4 acc[4][4];
#pragma unroll
    for (int i = 0; i < 4; ++i)
#pragma unroll
        for (int j = 0; j < 4; ++j) acc[i][j] = (floatx4)0.0f;

    for (int ks = 0; ks < KPH / 32; ++ks) {
        load_lds16(ga0, la0);
        load_lds16(ga1, la1);
        load_lds16(gb0, lb0);
        load_lds16(gb1, lb1);
        ga0 += 32; ga1 += 32; gb0 += 32; gb1 += 32;
        __syncthreads();

        bf16x8 afr[4], bfr[4];
#pragma unroll
        for (int mt = 0; mt < 4; ++mt) afr[mt] = *(const bf16x8*)(Ap + mt * 16 * 32);
#pragma unroll
        for (int nt = 0; nt < 4; ++nt) bfr[nt] = *(const bf16x8*)(Bp + nt * 16 * 32);
#pragma unroll
        for (int mt = 0; mt < 4; ++mt)
#pragma unroll
            for (int nt = 0; nt < 4; ++nt)
                acc[mt][nt] = __builtin_amdgcn_mfma_f32_16x16x32_bf16(
                    afr[mt], bfr[nt], acc[mt][nt], 0, 0, 0);
        __syncthreads();
    }

#pragma unroll
    for (int nt = 0; nt < 4; ++nt) {
        const int y = n0 + nw + nt * 16 + lm;
        if (y < CUTN) {
            const float lb = linb[y];
            const float gv = fcg[y];
#pragma unroll
            for (int mt = 0; mt < 4; ++mt) {
#pragma unroll
                for (int r = 0; r < 4; ++r) {
                    const int m = m0 + mw + mt * 16 + lq * 4 + r;
                    if (m < MROWS) {
                        const float v = (acc[mt][nt][r] + lb) * gv;
                        const float msk = 1.0f / (1.0f + __expf(-2.0f * v));
                        unsigned* p = tbu + (size_t)m * (TBP / 2) + y;
                        const unsigned u = *p;
                        const float re = bf2f((unsigned short)(u & 0xffffu)) * msk;
                        const float im = bf2f((unsigned short)(u >> 16)) * msk;
                        *p = (unsigned)f2bf(re) | ((unsigned)f2bf(im) << 16);
                    }
                }
            }
        }
    }
}

// ---------------------------------------------------------------------------
// k_convtm (MFMA): d[m][r] = A(tb2 windows) * Wd^T, fused sigmoid softmax.
// 64x128 tile (grid 1024 -> 4 blocks/CU; old 512-block grid capped at 2),
// BK=32, dbuf 24KB, counted vmcnt(3), same 64B-row swizzle as k_conv1m.
// Waves 2Mx2N: each wave owns 32x64 (acc[2][4], 8 MFMA/step, 130 steps).
// ---------------------------------------------------------------------------
__global__ __launch_bounds__(256) void k_convtm(
    const unsigned short* __restrict__ tb2, const unsigned short* __restrict__ wdb,
    float* __restrict__ out)
{
    extern __shared__ __align__(16) char lds[];   // 2 x (A 4KB + B 8KB) = 24KB

    const int m0 = blockIdx.x * 64, n0 = blockIdx.y * 128;
    const int b   = m0 >> 10;
    const int ml0 = m0 & 1023;
    const int tid = threadIdx.x;

    const unsigned short* tbb = tb2 + (size_t)b * FLATB;
    // A: 64 rows x 32 el = 4KB = 256 chunks (1/thread); B: 128 rows = 512 (2/thread)
    const unsigned short* gaA;
    const unsigned short* gB[2];
    int qaA, qB[2];
    {
        const int c = tid;                       // A chunk 0..255
        const int row = c >> 2;                  // 0..63
        const int colb = (c & 3) * 16;
        const int es = (colb ^ (((row >> 1) & 3) << 4)) >> 1;
        qaA = c * 16;
        gaA = tbb + (size_t)(ml0 + row + 1) * TBP + es;
    }
#pragma unroll
    for (int i = 0; i < 2; ++i) {
        const int c = i * 256 + tid;             // B chunk 0..511
        const int row = c >> 2;                  // 0..127
        const int colb = (c & 3) * 16;
        const int es = (colb ^ (((row >> 1) & 3) << 4)) >> 1;
        qB[i] = 4096 + c * 16;
        gB[i] = wdb + (size_t)(n0 + row) * KPC + es;
    }

    const int wave = tid >> 6, lane = tid & 63;
    const int lm = lane & 15, lq = lane >> 4;
    const int mw = (wave & 1) * 32, nw = (wave >> 1) * 64;
    const int swz = ((lm >> 1) & 3) << 4;
    const int abo = (mw + lm) * 64 + ((lq * 16) ^ swz);
    const int bbo = 4096 + (nw + lm) * 64 + ((lq * 16) ^ swz);

    floatx4 acc[2][4];
#pragma unroll
    for (int i = 0; i < 2; ++i)
#pragma unroll
        for (int j = 0; j < 4; ++j) acc[i][j] = (floatx4)0.0f;

    // prologue: issue K-tile 0 into buf 0 (3 loads in flight)
    load_lds16(gaA, lds + qaA);
    gaA += 32;
#pragma unroll
    for (int i = 0; i < 2; ++i) {
        load_lds16(gB[i], lds + qB[i]);
        gB[i] += 32;
    }

    for (int t = 0; t < KPC / 32 - 1; ++t) {
        char* cur = lds + (t & 1) * 12288;
        char* nxt = lds + ((t + 1) & 1) * 12288;

        load_lds16(gaA, nxt + qaA);
        gaA += 32;
#pragma unroll
        for (int i = 0; i < 2; ++i) {
            load_lds16(gB[i], nxt + qB[i]);
            gB[i] += 32;
        }
        asm volatile("s_waitcnt vmcnt(3)" ::: "memory");
        __builtin_amdgcn_sched_barrier(0);
        __builtin_amdgcn_s_barrier();

        bf16x8 afr[2], bfr[4];
#pragma unroll
        for (int mt = 0; mt < 2; ++mt)
            afr[mt] = *(const bf16x8*)(cur + abo + mt * 1024);
#pragma unroll
        for (int nt = 0; nt < 4; ++nt)
            bfr[nt] = *(const bf16x8*)(cur + bbo + nt * 1024);
        asm volatile("s_waitcnt lgkmcnt(0)" ::: "memory");
        __builtin_amdgcn_sched_barrier(0);
        __builtin_amdgcn_s_barrier();

        __builtin_amdgcn_s_setprio(1);
#pragma unroll
        for (int mt = 0; mt < 2; ++mt)
#pragma unroll
            for (int nt = 0; nt < 4; ++nt)
                acc[mt][nt] = __builtin_amdgcn_mfma_f32_16x16x32_bf16(
                    afr[mt], bfr[nt], acc[mt][nt], 0, 0, 0);
        __builtin_amdgcn_s_setprio(0);
    }
    // peeled final K-tile
    {
        char* cur = lds + ((KPC / 32 - 1) & 1) * 12288;
        asm volatile("s_waitcnt vmcnt(0)" ::: "memory");
        __builtin_amdgcn_sched_barrier(0);
        __builtin_amdgcn_s_barrier();

        bf16x8 afr[2], bfr[4];
#pragma unroll
        for (int mt = 0; mt < 2; ++mt)
            afr[mt] = *(const bf16x8*)(cur + abo + mt * 1024);
#pragma unroll
        for (int nt = 0; nt < 4; ++nt)
            bfr[nt] = *(const bf16x8*)(cur + bbo + nt * 1024);
#pragma unroll
        for (int mt = 0; mt < 2; ++mt)
#pragma unroll
            for (int nt = 0; nt < 4; ++nt)
                acc[mt][nt] = __builtin_amdgcn_mfma_f32_16x16x32_bf16(
                    afr[mt], bfr[nt], acc[mt][nt], 0, 0, 0);
    }

    float* ob = out + (size_t)b * 2 * TIME_N;
#pragma unroll
    for (int nt = 0; nt < 4; ++nt) {
        const int n = n0 + nw + nt * 16 + lm;
#pragma unroll
        for (int mt = 0; mt < 2; ++mt) {
#pragma unroll
            for (int r = 0; r < 4; ++r) {
                const int m = ml0 + mw + mt * 16 + lq * 4 + r;
                const float d = acc[mt][nt][r];
                const float p0 = 1.0f / (1.0f + __expf(-d));
                const int tau = m * 256 + n;
                ob[tau]          = p0;
                ob[TIME_N + tau] = 1.0f - p0;
            }
        }
    }
}

extern "C" void kernel_launch(void* const* d_in, const int* in_sizes, int n_in,
                              void* d_out, int out_size, void* d_ws, size_t ws_size,
                              hipStream_t stream)
{
    const float* x    = (const float*)d_in[0];
    const float* c1w  = (const float*)d_in[1];
    const float* ing  = (const float*)d_in[2];
    const float* cb1w = (const float*)d_in[3];
    const float* cb1b = (const float*)d_in[4];
    const float* cb2w = (const float*)d_in[5];
    const float* cb2b = (const float*)d_in[6];
    const float* linw = (const float*)d_in[7];
    const float* linb = (const float*)d_in[8];
    const float* fcg  = (const float*)d_in[9];
    const float* ctw  = (const float*)d_in[10];
    float* out = (float*)d_out;

    // ---- workspace layout (all bf16) ----
    unsigned short* tb2 = (unsigned short*)d_ws;           // 32*1029*1040
    unsigned short* h   = tb2 + (size_t)BATCH * FLATB;     // 33024*544
    unsigned short* wlb = h + (size_t)MP * KPH;            // 640*544
    unsigned short* xb  = wlb + (size_t)NPH * KPH;         // 32*XLEN
    unsigned short* wbf = xb + (size_t)BATCH * XLEN;       // 1152*1024
    unsigned short* wdb = wbf + (size_t)CPAD * KW;         // 256*4160

    hipLaunchKernelGGL(k_prep, dim3(PB_TOTAL), dim3(256), 0, stream,
                       x, c1w, linw, ctw, xb, wbf, wlb, wdb);
    hipLaunchKernelGGL(k_conv1m, dim3(BATCH * 9 * 9), dim3(256), 32768, stream,
                       xb, wbf, ing, cb1w, cb1b, cb2w, cb2b, tb2, h);
    hipLaunchKernelGGL(k_maskm, dim3(MP / 128, NPH / 128), dim3(256), 0, stream,
                       h, wlb, linb, fcg, (unsigned*)tb2);
    hipLaunchKernelGGL(k_convtm, dim3(512, 2), dim3(256), 24576, stream,
                       tb2, wdb, out);
}

// Round 7
// 445.715 us; speedup vs baseline: 1.1586x; 1.1586x over previous
//
#include <hip/hip_runtime.h>
#include <cstddef>
#include <cstdint>

#define TIME_N 262144
#define BATCH  32
#define KW     1024
#define ST     256
#define CUTN   513
#define TCN    1026
#define FN     1029   // frames
#define FPAD   1152
#define CPAD   1152
#define XLEN   (FPAD * ST + KW)   // 295936 bf16 per batch row
#define XBLK   (XLEN / 256)       // 1156

// mask GEMM dims
#define MROWS  (BATCH * FN)   // 32928
#define MP     33024          // 258*128
#define KPH    544            // 513 -> 17*32
#define NPH    640            // 513 -> 5*128
// convT GEMM dims / flat bf16 t layout (re/im PAIR-INTERLEAVED: col 2y=re_y, 2y+1=im_y)
#define TBP    1040           // flat bf16 t row stride (16B-aligned, 65*16)
#define FLATB  (FN * TBP)     // per-batch flat size
#define KPC    4160           // 4*1040 = 65*64

// k_prep block ranges
#define PB_XPAD  (XBLK * BATCH)            // 36992
#define PB_WBF   (PB_XPAD + CPAD)          // +1152
#define PB_WLIN  (PB_WBF + NPH)            // +640
#define PB_TOTAL (PB_WLIN + KPC)           // +4160

typedef __bf16 bf16x8 __attribute__((ext_vector_type(8)));
typedef float floatx4 __attribute__((ext_vector_type(4)));
typedef int   intx4   __attribute__((ext_vector_type(4)));

__device__ __forceinline__ unsigned short f2bf(float f) {
    union { float f; unsigned u; } v; v.f = f;
    unsigned r = (v.u + 0x7fffu + ((v.u >> 16) & 1u)) >> 16;
    return (unsigned short)r;
}
__device__ __forceinline__ float bf2f(unsigned short s) {
    union { unsigned u; float f; } v; v.u = ((unsigned)s) << 16;
    return v.f;
}
// interleaved column n -> original channel index
__device__ __forceinline__ int permch(int n) {
    return (n & 1) ? (CUTN + (n >> 1)) : (n >> 1);
}

__device__ __forceinline__ void load_lds16(const void* g, void* l) {
    __builtin_amdgcn_global_load_lds(
        (const __attribute__((address_space(1))) void*)g,
        (__attribute__((address_space(3))) void*)l, 16, 0, 0);
}

// ---------------------------------------------------------------------------
// k_prep: all input-conversion work in ONE launch, split by blockIdx range.
// ---------------------------------------------------------------------------
__global__ __launch_bounds__(256) void k_prep(
    const float* __restrict__ x, const float* __restrict__ c1w,
    const float* __restrict__ lw, const float* __restrict__ wct,
    unsigned short* __restrict__ xb, unsigned short* __restrict__ wbf,
    unsigned short* __restrict__ wlb, unsigned short* __restrict__ wdb)
{
    const int bid = blockIdx.x;
    if (bid < PB_XPAD) {
        const int b = bid / XBLK;
        const int p = (bid - b * XBLK) * 256 + threadIdx.x;
        const int g = p - KW;
        float v = (g >= 0 && g < TIME_N) ? x[(size_t)b * TIME_N + g] : 0.0f;
        xb[(size_t)b * XLEN + p] = f2bf(v);
    } else if (bid < PB_WBF) {
        const int n = bid - PB_XPAD;              // 0..1151 interleaved row
        const int ch = (n < TCN) ? permch(n) : 0;
        for (int k = threadIdx.x; k < KW; k += 256) {
            float v = (n < TCN) ? c1w[(size_t)ch * KW + k] : 0.0f;
            wbf[(size_t)n * KW + k] = f2bf(v);
        }
    } else if (bid < PB_WLIN) {
        const int n = bid - PB_WBF;               // 0..639
        for (int k = threadIdx.x; k < KPH; k += 256) {
            float v = (n < CUTN && k < CUTN) ? lw[(size_t)n * CUTN + k] : 0.0f;
            wlb[(size_t)n * KPH + k] = f2bf(v);
        }
    } else {
        const int k = bid - PB_WLIN;              // 0..4159
        const int r = threadIdx.x;                // 0..255
        const int j = k / TBP;
        const int n = k - j * TBP;
        float v = 0.0f;
        if (n < TCN) {
            const int ch = permch(n);
            const int widx = (3 - j) * 256 + r;
            v = wct[(size_t)(2 * ch) * KW + widx] -
                wct[(size_t)(2 * ch + 1) * KW + widx];
        }
        wdb[(size_t)r * KPC + k] = f2bf(v);
    }
}

// ---------------------------------------------------------------------------
// k_conv1m (MFMA): conv1 bf16 GEMM, 128x128 tile, BK=32, dbuf'd counted-vmcnt
// K-loop (round-6 best, kept verbatim). NEW: LDS-STAGED EPILOGUE — the old
// epilogue scattered 4B/2B stores across 8 rows per inst (WRITE_SIZE 227MB vs
// 104MB ideal: partial-line writeback). Now: results go to a 48KB LDS stage
// (tb2 32KB @0, h 16KB @32KB), then coalesced copy-out with full-line 16B/lane
// stores. Math/order identical -> absmax unchanged.
// ---------------------------------------------------------------------------
__global__ __launch_bounds__(256) void k_conv1m(
    const unsigned short* __restrict__ xb, const unsigned short* __restrict__ wb,
    const float* __restrict__ gamma,
    const float* __restrict__ c1w, const float* __restrict__ c1b,
    const float* __restrict__ c2w, const float* __restrict__ c2b,
    unsigned short* __restrict__ tb2, unsigned short* __restrict__ h)
{
    extern __shared__ __align__(16) char lds[];   // 48KB (K-loop uses first 32KB)

    const int flat = blockIdx.x;
    const int xcd = flat & 7;
    const int idx = flat >> 3;              // 0..323
    const int cb  = idx % 9;
    const int pr  = xcd * 36 + idx / 9;     // 0..287 (b,fb) pair
    const int b   = pr / 9;
    const int fb  = pr % 9;
    const int f0 = fb * 128, c0 = cb * 128;
    const int tid = threadIdx.x;

    // staging: 512 chunks of 16B per operand; 2 chunks/thread/operand
    const unsigned short* xrow = xb + (size_t)b * XLEN;
    const unsigned short* ga[2];
    const unsigned short* gb[2];
    int qa[2];
#pragma unroll
    for (int i = 0; i < 2; ++i) {
        const int c = i * 256 + tid;             // chunk 0..511
        const int row = c >> 2;                  // 0..127
        const int colb = (c & 3) * 16;           // byte col in 64B row
        const int es = (colb ^ (((row >> 1) & 3) << 4)) >> 1;  // inv-swz elem
        qa[i] = c * 16;                          // linear LDS byte offset
        ga[i] = xrow + (size_t)(f0 + row) * ST + es;
        gb[i] = wb + (size_t)(c0 + row) * KW + es;
    }

    const int wave = tid >> 6, lane = tid & 63;
    const int lm = lane & 15, lq = lane >> 4;
    const int mw = (wave & 1) * 64, nw = (wave >> 1) * 64;
    const int swz = ((lm >> 1) & 3) << 4;
    const int abo = (mw + lm) * 64 + ((lq * 16) ^ swz);
    const int bbo = 8192 + (nw + lm) * 64 + ((lq * 16) ^ swz);

    floatx4 acc[4][4];
#pragma unroll
    for (int i = 0; i < 4; ++i)
#pragma unroll
        for (int j = 0; j < 4; ++j) acc[i][j] = (floatx4)0.0f;

    // prologue: issue K-tile 0 into buf 0 (4 loads in flight)
#pragma unroll
    for (int i = 0; i < 2; ++i) {
        load_lds16(ga[i], lds + qa[i]);
        load_lds16(gb[i], lds + 8192 + qa[i]);
        ga[i] += 32; gb[i] += 32;
    }

    for (int t = 0; t < KW / 32 - 1; ++t) {
        char* cur = lds + (t & 1) * 16384;
        char* nxt = lds + ((t + 1) & 1) * 16384;

#pragma unroll
        for (int i = 0; i < 2; ++i) {
            load_lds16(ga[i], nxt + qa[i]);
            load_lds16(gb[i], nxt + 8192 + qa[i]);
            ga[i] += 32; gb[i] += 32;
        }
        asm volatile("s_waitcnt vmcnt(4)" ::: "memory");
        __builtin_amdgcn_sched_barrier(0);
        __builtin_amdgcn_s_barrier();

        bf16x8 afr[4], bfr[4];
#pragma unroll
        for (int mt = 0; mt < 4; ++mt)
            afr[mt] = *(const bf16x8*)(cur + abo + mt * 1024);
#pragma unroll
        for (int nt = 0; nt < 4; ++nt)
            bfr[nt] = *(const bf16x8*)(cur + bbo + nt * 1024);
        asm volatile("s_waitcnt lgkmcnt(0)" ::: "memory");
        __builtin_amdgcn_sched_barrier(0);
        __builtin_amdgcn_s_barrier();

        __builtin_amdgcn_s_setprio(1);
#pragma unroll
        for (int mt = 0; mt < 4; ++mt)
#pragma unroll
            for (int nt = 0; nt < 4; ++nt)
                acc[mt][nt] = __builtin_amdgcn_mfma_f32_16x16x32_bf16(
                    afr[mt], bfr[nt], acc[mt][nt], 0, 0, 0);
        __builtin_amdgcn_s_setprio(0);
    }
    // peeled final K-tile
    {
        char* cur = lds + ((KW / 32 - 1) & 1) * 16384;
        asm volatile("s_waitcnt vmcnt(0)" ::: "memory");
        __builtin_amdgcn_sched_barrier(0);
        __builtin_amdgcn_s_barrier();

        bf16x8 afr[4], bfr[4];
#pragma unroll
        for (int mt = 0; mt < 4; ++mt)
            afr[mt] = *(const bf16x8*)(cur + abo + mt * 1024);
#pragma unroll
        for (int nt = 0; nt < 4; ++nt)
            bfr[nt] = *(const bf16x8*)(cur + bbo + nt * 1024);
#pragma unroll
        for (int mt = 0; mt < 4; ++mt)
#pragma unroll
            for (int nt = 0; nt < 4; ++nt)
                acc[mt][nt] = __builtin_amdgcn_mfma_f32_16x16x32_bf16(
                    afr[mt], bfr[nt], acc[mt][nt], 0, 0, 0);
    }
    __syncthreads();          // all fragment reads done -> LDS reusable

    // ---- epilogue phase E1: compute + stage into LDS ----
    // tb2 stage: [fl 0..127][nl 0..255 bf16] @ 0..32KB (row = 256B)
    // h   stage: [fl 0..127][y  0..63  bf16] @ 32KB..48KB (row = 128B)
    float w1[16], b1[8], w2[8];
#pragma unroll
    for (int o = 0; o < 8; ++o) {
        w1[2 * o]     = c1w[2 * o];
        w1[2 * o + 1] = c1w[2 * o + 1];
        b1[o] = c1b[o];
        w2[o] = c2w[o];
    }
    const float b2v = c2b[0];
    const bool evenlane = ((lane & 1) == 0);

#pragma unroll
    for (int nt = 0; nt < 4; ++nt) {
        const int nl = nw + nt * 16 + lm;        // local col 0..127
        const int n = c0 + nl;
        const bool valid_c = (n < TCN);
        const float gv = valid_c ? gamma[permch(n)] : 0.0f;
        const int nbl = nl & ~1;                 // local pair col
        const int yl  = nl >> 1;                 // local ybase 0..63
#pragma unroll
        for (int mt = 0; mt < 4; ++mt) {
#pragma unroll
            for (int rp = 0; rp < 2; ++rp) {
                const int ra = rp * 2;
                const int fl = mw + mt * 16 + lq * 4 + ra;   // local frame
                const float ua = acc[mt][nt][ra] * gv;
                const float ub = acc[mt][nt][ra + 1] * gv;
                const float ta  = 2.0f / (1.0f + __expf(-2.0f * ua)) - 1.0f;
                const float tbv = 2.0f / (1.0f + __expf(-2.0f * ub)) - 1.0f;
                const float sa = __shfl_xor(ta, 1);
                const float sb = __shfl_xor(tbv, 1);
                // even lane owns frame fl (re=ta, im=sa);
                // odd lane owns frame fl+1 (re=sb, im=tbv)
                const int  fme = evenlane ? fl : (fl + 1);
                const float re = evenlane ? ta : sb;
                const float im = evenlane ? sa : tbv;
                const unsigned pr2 = (unsigned)f2bf(re) |
                                     ((unsigned)f2bf(im) << 16);
                *(unsigned*)(lds + fme * 256 + nbl * 2) = pr2;
                float a2 = b2v;
#pragma unroll
                for (int o = 0; o < 8; ++o) {
                    const float a1 = fmaxf(
                        re * w1[2 * o] + im * w1[2 * o + 1] + b1[o], 0.0f);
                    a2 += a1 * w2[o];
                }
                *(unsigned short*)(lds + 32768 + fme * 128 + yl * 2) =
                    f2bf(fmaxf(a2, 0.0f));
            }
        }
    }
    __syncthreads();

    // ---- epilogue phase E2: coalesced copy-out (full-line stores) ----
    // tb2: 2048 chunks of 16B (16 chunks/row); valid pair-chunks per row:
    const int vch = min(16, max(0, (520 - (c0 >> 1)) >> 2));   // 16B = 4 pairs
    unsigned short* tbb = tb2 + (size_t)b * FLATB;
#pragma unroll
    for (int i = 0; i < 8; ++i) {
        const int c = i * 256 + tid;             // chunk 0..2047
        const int fl = c >> 4;                   // row 0..127
        const int c16 = c & 15;                  // chunk in row
        if (f0 + fl < FN && c16 < vch) {
            const intx4 v = *(const intx4*)(lds + c * 16);
            *(intx4*)(tbb + (size_t)(f0 + fl) * TBP + (c0 + c16 * 8)) = v;
        }
    }
    // h: 1024 chunks of 16B (8 chunks/row); valid short-chunks per row:
    const int vhc = min(8, max(0, (544 - (c0 >> 1)) >> 3));    // 16B = 8 shorts
#pragma unroll
    for (int i = 0; i < 4; ++i) {
        const int c = i * 256 + tid;             // chunk 0..1023
        const int fl = c >> 3;                   // row 0..127
        const int c16 = c & 7;
        if (f0 + fl < FN && c16 < vhc) {
            const intx4 v = *(const intx4*)(lds + 32768 + c * 16);
            *(intx4*)(h + ((size_t)b * FN + f0 + fl) * KPH +
                      ((c0 >> 1) + c16 * 8)) = v;
        }
    }
}

// ---------------------------------------------------------------------------
// k_maskm (MFMA): hh = H * Wlin^T; mask = sigmoid(2*(hh+b)*g);
// RMW: one aligned uint per (m,y) scales the (re,im) pair in tb2.
// (unchanged; KPH=544 is not divisible by 64)
// ---------------------------------------------------------------------------
__global__ __launch_bounds__(256) void k_maskm(
    const unsigned short* __restrict__ h, const unsigned short* __restrict__ wlb,
    const float* __restrict__ linb, const float* __restrict__ fcg,
    unsigned* __restrict__ tbu)
{
    __shared__ __align__(16) unsigned short As[128 * 32];
    __shared__ __align__(16) unsigned short Bs[128 * 32];

    const int m0 = blockIdx.x * 128, n0 = blockIdx.y * 128;
    const int tid = threadIdx.x;

    const int s0 = tid, s1 = tid + 256;
    const int ar0 = s0 >> 2, aq0 = s0 & 3;
    const int ar1 = s1 >> 2, aq1 = s1 & 3;
    const unsigned short* ga0 = h + (size_t)(m0 + ar0) * KPH + aq0 * 8;
    const unsigned short* ga1 = h + (size_t)(m0 + ar1) * KPH + aq1 * 8;
    const unsigned short* gb0 = wlb + (size_t)(n0 + ar0) * KPH + aq0 * 8;
    const unsigned short* gb1 = wlb + (size_t)(n0 + ar1) * KPH + aq1 * 8;
    unsigned short* la0 = &As[s0 * 8];
    unsigned short* la1 = &As[s1 * 8];
    unsigned short* lb0 = &Bs[s0 * 8];
    unsigned short* lb1 = &Bs[s1 * 8];

    const int wave = tid >> 6, lane = tid & 63;
    const int lm = lane & 15, lq = lane >> 4;
    const int mw = (wave & 1) * 64, nw = (wave >> 1) * 64;
    const unsigned short* Ap = &As[(mw + lm) * 32 + lq * 8];
    const unsigned short* Bp = &Bs[(nw + lm) * 32 + lq * 8];

    floatx4 acc[4][4];
#pragma unroll
    for (int i = 0; i < 4; ++i)
#pragma unroll
        for (int j = 0; j < 4; ++j) acc[i][j] = (floatx4)0.0f;

    for (int ks = 0; ks < KPH / 32; ++ks) {
        load_lds16(ga0, la0);
        load_lds16(ga1, la1);
        load_lds16(gb0, lb0);
        load_lds16(gb1, lb1);
        ga0 += 32; ga1 += 32; gb0 += 32; gb1 += 32;
        __syncthreads();

        bf16x8 afr[4], bfr[4];
#pragma unroll
        for (int mt = 0; mt < 4; ++mt) afr[mt] = *(const bf16x8*)(Ap + mt * 16 * 32);
#pragma unroll
        for (int nt = 0; nt < 4; ++nt) bfr[nt] = *(const bf16x8*)(Bp + nt * 16 * 32);
#pragma unroll
        for (int mt = 0; mt < 4; ++mt)
#pragma unroll
            for (int nt = 0; nt < 4; ++nt)
                acc[mt][nt] = __builtin_amdgcn_mfma_f32_16x16x32_bf16(
                    afr[mt], bfr[nt], acc[mt][nt], 0, 0, 0);
        __syncthreads();
    }

#pragma unroll
    for (int nt = 0; nt < 4; ++nt) {
        const int y = n0 + nw + nt * 16 + lm;
        if (y < CUTN) {
            const float lb = linb[y];
            const float gv = fcg[y];
#pragma unroll
            for (int mt = 0; mt < 4; ++mt) {
#pragma unroll
                for (int r = 0; r < 4; ++r) {
                    const int m = m0 + mw + mt * 16 + lq * 4 + r;
                    if (m < MROWS) {
                        const float v = (acc[mt][nt][r] + lb) * gv;
                        const float msk = 1.0f / (1.0f + __expf(-2.0f * v));
                        unsigned* p = tbu + (size_t)m * (TBP / 2) + y;
                        const unsigned u = *p;
                        const float re = bf2f((unsigned short)(u & 0xffffu)) * msk;
                        const float im = bf2f((unsigned short)(u >> 16)) * msk;
                        *p = (unsigned)f2bf(re) | ((unsigned)f2bf(im) << 16);
                    }
                }
            }
        }
    }
}

// ---------------------------------------------------------------------------
// k_convtm (MFMA): d[m][r] = A(tb2 windows) * Wd^T, fused sigmoid softmax.
// Round-4 geometry (128x128, BK=64, T3-minimum dbuf, 2x32KB) + NEW LDS-staged
// output: p0 block (128x128 f32 = 64KB) staged in LDS after the K-loop, then
// coalesced full-line copy-out of p and 1-p (old path: 64B-partial lines).
// ---------------------------------------------------------------------------
__global__ __launch_bounds__(256) void k_convtm(
    const unsigned short* __restrict__ tb2, const unsigned short* __restrict__ wdb,
    float* __restrict__ out)
{
    extern __shared__ __align__(16) char lds[];   // 64KB (2x32KB dbuf; reused as stage)

    const int m0 = blockIdx.x * 128, n0 = blockIdx.y * 128;
    const int b   = m0 >> 10;
    const int ml0 = m0 & 1023;
    const int tid = threadIdx.x;

    const unsigned short* tbb = tb2 + (size_t)b * FLATB;
    const unsigned short* ga[4];
    const unsigned short* gb[4];
    int qa[4];
#pragma unroll
    for (int i = 0; i < 4; ++i) {
        const int c = i * 256 + tid;             // chunk 0..1023
        const int row = c >> 3;                  // 0..127
        const int colb = (c & 7) * 16;
        const int es = (colb ^ ((row & 7) << 4)) >> 1;
        qa[i] = c * 16;
        ga[i] = tbb + (size_t)(ml0 + row + 1) * TBP + es;
        gb[i] = wdb + (size_t)(n0 + row) * KPC + es;
    }

    const int wave = tid >> 6, lane = tid & 63;
    const int lm = lane & 15, lq = lane >> 4;
    const int mw = (wave & 1) * 64, nw = (wave >> 1) * 64;
    const int swz = (lm & 7) << 4;
    int abo[2], bbo[2];
#pragma unroll
    for (int ks = 0; ks < 2; ++ks) {
        abo[ks] = (mw + lm) * 128 + ((ks * 64 + lq * 16) ^ swz);
        bbo[ks] = 16384 + (nw + lm) * 128 + ((ks * 64 + lq * 16) ^ swz);
    }

    floatx4 acc[4][4];
#pragma unroll
    for (int i = 0; i < 4; ++i)
#pragma unroll
        for (int j = 0; j < 4; ++j) acc[i][j] = (floatx4)0.0f;

    // prologue: stage K-tile 0 into buf 0
#pragma unroll
    for (int i = 0; i < 4; ++i) {
        load_lds16(ga[i], lds + qa[i]);
        load_lds16(gb[i], lds + 16384 + qa[i]);
        ga[i] += 64; gb[i] += 64;
    }
    __syncthreads();

    for (int t = 0; t < KPC / 64; ++t) {
        char* cur = lds + (t & 1) * 32768;
        char* nxt = lds + ((t + 1) & 1) * 32768;

        if (t + 1 < KPC / 64) {
#pragma unroll
            for (int i = 0; i < 4; ++i) {
                load_lds16(ga[i], nxt + qa[i]);
                load_lds16(gb[i], nxt + 16384 + qa[i]);
                ga[i] += 64; gb[i] += 64;
            }
        }

        bf16x8 afr[4][2], bfr[4][2];
#pragma unroll
        for (int mt = 0; mt < 4; ++mt)
#pragma unroll
            for (int ks = 0; ks < 2; ++ks)
                afr[mt][ks] = *(const bf16x8*)(cur + abo[ks] + mt * 2048);
#pragma unroll
        for (int nt = 0; nt < 4; ++nt)
#pragma unroll
            for (int ks = 0; ks < 2; ++ks)
                bfr[nt][ks] = *(const bf16x8*)(cur + bbo[ks] + nt * 2048);
#pragma unroll
        for (int mt = 0; mt < 4; ++mt)
#pragma unroll
            for (int nt = 0; nt < 4; ++nt)
#pragma unroll
                for (int ks = 0; ks < 2; ++ks)
                    acc[mt][nt] = __builtin_amdgcn_mfma_f32_16x16x32_bf16(
                        afr[mt][ks], bfr[nt][ks], acc[mt][nt], 0, 0, 0);
        __syncthreads();
    }

    // ---- E1: stage p0 block into LDS: [ml 0..127][nl 0..127] f32 (64KB) ----
#pragma unroll
    for (int nt = 0; nt < 4; ++nt) {
        const int nl = nw + nt * 16 + lm;
#pragma unroll
        for (int mt = 0; mt < 4; ++mt) {
#pragma unroll
            for (int r = 0; r < 4; ++r) {
                const int ml = mw + mt * 16 + lq * 4 + r;
                const float d = acc[mt][nt][r];
                const float p0 = 1.0f / (1.0f + __expf(-d));
                *(float*)(lds + ml * 512 + nl * 4) = p0;
            }
        }
    }
    __syncthreads();

    // ---- E2: coalesced copy-out (full 128B lines), p and 1-p ----
    float* ob = out + (size_t)b * 2 * TIME_N;
#pragma unroll
    for (int i = 0; i < 16; ++i) {
        const int c = i * 256 + tid;             // chunk 0..4095 (16B)
        const int ml = c >> 5;                   // row 0..127
        const int c16 = c & 31;                  // chunk in row
        const floatx4 v = *(const floatx4*)(lds + c * 16);
        floatx4 w;
        w[0] = 1.0f - v[0]; w[1] = 1.0f - v[1];
        w[2] = 1.0f - v[2]; w[3] = 1.0f - v[3];
        const int tau = (ml0 + ml) * 256 + n0 + c16 * 4;
        *(floatx4*)(ob + tau)          = v;
        *(floatx4*)(ob + TIME_N + tau) = w;
    }
}

extern "C" void kernel_launch(void* const* d_in, const int* in_sizes, int n_in,
                              void* d_out, int out_size, void* d_ws, size_t ws_size,
                              hipStream_t stream)
{
    const float* x    = (const float*)d_in[0];
    const float* c1w  = (const float*)d_in[1];
    const float* ing  = (const float*)d_in[2];
    const float* cb1w = (const float*)d_in[3];
    const float* cb1b = (const float*)d_in[4];
    const float* cb2w = (const float*)d_in[5];
    const float* cb2b = (const float*)d_in[6];
    const float* linw = (const float*)d_in[7];
    const float* linb = (const float*)d_in[8];
    const float* fcg  = (const float*)d_in[9];
    const float* ctw  = (const float*)d_in[10];
    float* out = (float*)d_out;

    // ---- workspace layout (all bf16) ----
    unsigned short* tb2 = (unsigned short*)d_ws;           // 32*1029*1040
    unsigned short* h   = tb2 + (size_t)BATCH * FLATB;     // 33024*544
    unsigned short* wlb = h + (size_t)MP * KPH;            // 640*544
    unsigned short* xb  = wlb + (size_t)NPH * KPH;         // 32*XLEN
    unsigned short* wbf = xb + (size_t)BATCH * XLEN;       // 1152*1024
    unsigned short* wdb = wbf + (size_t)CPAD * KW;         // 256*4160

    hipLaunchKernelGGL(k_prep, dim3(PB_TOTAL), dim3(256), 0, stream,
                       x, c1w, linw, ctw, xb, wbf, wlb, wdb);
    hipLaunchKernelGGL(k_conv1m, dim3(BATCH * 9 * 9), dim3(256), 49152, stream,
                       xb, wbf, ing, cb1w, cb1b, cb2w, cb2b, tb2, h);
    hipLaunchKernelGGL(k_maskm, dim3(MP / 128, NPH / 128), dim3(256), 0, stream,
                       h, wlb, linb, fcg, (unsigned*)tb2);
    hipLaunchKernelGGL(k_convtm, dim3(256, 2), dim3(256), 65536, stream,
                       tb2, wdb, out);
}